// Round 4
// baseline (30.121 us; speedup 1.0000x reference)
//
#include <hip/hip_runtime.h>

#define EPS 1e-5f

// Geometry: inp (25,2,128,8,8) fp32 -> 3200 (n,s) instances, hw=64, c=2.
// InstanceNorm over (c,hw)=128; qkv = y @ qkv_w^T + b (192 rows);
// c=2 collapses linear attn to 2x2 M = q k^T, attn = v + M v;
// out = attn @ proj_w^T + proj_b + inp.  Output fp32.
//
// One instance per 64-thread block (3200 blocks = 12.5 waves/CU, ~8% tail):
//  - thread t owns qkv rows {t, 64+t, 128+t}: each LDS y read reused 3x
//  - 2x2 M via 64-lane butterfly; proj row t per thread; residual in regs.
// Weight rows re-read per wave; L1/L2 absorb (64 KB working set).

__global__ __launch_bounds__(64)
void attn_fused(const float* __restrict__ inp,
                const float* __restrict__ qkv_w,
                const float* __restrict__ qkv_b,
                const float* __restrict__ proj_w,
                const float* __restrict__ proj_b,
                float* __restrict__ out)
{
    const int t = threadIdx.x;        // lane = hw column = output column
    const int g = blockIdx.x;         // instance id
    const int n = g >> 7;             // g / 128
    const int s = g & 127;            // g % 128

    __shared__ float y_lds[2][64];
    __shared__ float a_lds[2][64];

    // ---------------- Phase A: load + InstanceNorm ----------------
    // flat idx: n*16384 + c*8192 + s*64 + j
    const int base = n * 16384 + s * 64 + t;
    const float x0 = inp[base];
    const float x1 = inp[base + 8192];

    float s1 = x0 + x1;
    float s2 = fmaf(x0, x0, x1 * x1);
    #pragma unroll
    for (int m = 32; m >= 1; m >>= 1) {
        s1 += __shfl_xor(s1, m);
        s2 += __shfl_xor(s2, m);
    }
    const float mean = s1 * (1.0f / 128.0f);
    const float var  = s2 * (1.0f / 128.0f) - mean * mean;   // biased, like jnp.var
    const float rs   = rsqrtf(var + EPS);
    y_lds[0][t] = (x0 - mean) * rs;
    y_lds[1][t] = (x1 - mean) * rs;
    __syncthreads();

    // ---------------- Phase B: qkv rows t / 64+t / 128+t ----------------
    float aq0 = 0.f, aq1 = 0.f, ak0 = 0.f, ak1 = 0.f, av0 = 0.f, av1 = 0.f;
    const float4* qr = reinterpret_cast<const float4*>(qkv_w + (      t) * 64);
    const float4* kr = reinterpret_cast<const float4*>(qkv_w + ( 64 + t) * 64);
    const float4* vr = reinterpret_cast<const float4*>(qkv_w + (128 + t) * 64);

    #pragma unroll 4
    for (int j4 = 0; j4 < 16; ++j4) {
        const float4 y0 = *reinterpret_cast<const float4*>(&y_lds[0][j4 * 4]);
        const float4 y1 = *reinterpret_cast<const float4*>(&y_lds[1][j4 * 4]);
        const float4 wq = qr[j4];
        const float4 wk = kr[j4];
        const float4 wv = vr[j4];
        aq0 = fmaf(wq.x, y0.x, fmaf(wq.y, y0.y, fmaf(wq.z, y0.z, fmaf(wq.w, y0.w, aq0))));
        aq1 = fmaf(wq.x, y1.x, fmaf(wq.y, y1.y, fmaf(wq.z, y1.z, fmaf(wq.w, y1.w, aq1))));
        ak0 = fmaf(wk.x, y0.x, fmaf(wk.y, y0.y, fmaf(wk.z, y0.z, fmaf(wk.w, y0.w, ak0))));
        ak1 = fmaf(wk.x, y1.x, fmaf(wk.y, y1.y, fmaf(wk.z, y1.z, fmaf(wk.w, y1.w, ak1))));
        av0 = fmaf(wv.x, y0.x, fmaf(wv.y, y0.y, fmaf(wv.z, y0.z, fmaf(wv.w, y0.w, av0))));
        av1 = fmaf(wv.x, y1.x, fmaf(wv.y, y1.y, fmaf(wv.z, y1.z, fmaf(wv.w, y1.w, av1))));
    }
    const float q0 = aq0 + qkv_b[t];
    const float q1 = aq1 + qkv_b[t];
    const float k0 = ak0 + qkv_b[64 + t];
    const float k1 = ak1 + qkv_b[64 + t];
    const float v0 = av0 + qkv_b[128 + t];
    const float v1 = av1 + qkv_b[128 + t];

    // ---------------- Phase C: 2x2 M = q k^T (butterfly over 64 lanes) ----------------
    float p0 = q0 * k0, p1 = q0 * k1, p2 = q1 * k0, p3 = q1 * k1;
    #pragma unroll
    for (int m = 32; m >= 1; m >>= 1) {
        p0 += __shfl_xor(p0, m);
        p1 += __shfl_xor(p1, m);
        p2 += __shfl_xor(p2, m);
        p3 += __shfl_xor(p3, m);
    }
    a_lds[0][t] = v0 + fmaf(p0, v0, p1 * v1);
    a_lds[1][t] = v1 + fmaf(p2, v0, p3 * v1);
    __syncthreads();

    // ---------------- Phase D: proj + residual + store ----------------
    float ao0 = 0.f, ao1 = 0.f;
    const float4* pr = reinterpret_cast<const float4*>(proj_w + t * 64);
    #pragma unroll 4
    for (int j4 = 0; j4 < 16; ++j4) {
        const float4 w  = pr[j4];
        const float4 a0 = *reinterpret_cast<const float4*>(&a_lds[0][j4 * 4]);
        const float4 a1 = *reinterpret_cast<const float4*>(&a_lds[1][j4 * 4]);
        ao0 = fmaf(w.x, a0.x, fmaf(w.y, a0.y, fmaf(w.z, a0.z, fmaf(w.w, a0.w, ao0))));
        ao1 = fmaf(w.x, a1.x, fmaf(w.y, a1.y, fmaf(w.z, a1.z, fmaf(w.w, a1.w, ao1))));
    }
    const float pb = proj_b[t];
    out[base]        = ao0 + pb + x0;
    out[base + 8192] = ao1 + pb + x1;
}

extern "C" void kernel_launch(void* const* d_in, const int* in_sizes, int n_in,
                              void* d_out, int out_size, void* d_ws, size_t ws_size,
                              hipStream_t stream) {
    const float* inp    = (const float*)d_in[0];
    const float* qkv_w  = (const float*)d_in[1];
    const float* qkv_b  = (const float*)d_in[2];
    const float* proj_w = (const float*)d_in[3];
    const float* proj_b = (const float*)d_in[4];
    float* out = (float*)d_out;

    // one instance per 64-thread block
    attn_fused<<<dim3(3200), dim3(64), 0, stream>>>(inp, qkv_w, qkv_b, proj_w, proj_b, out);
}

// Round 5
// 9.878 us; speedup vs baseline: 3.0492x; 3.0492x over previous
//
#include <hip/hip_runtime.h>

#define EPS 1e-5f

// Geometry: inp (25,2,128,8,8) fp32 -> 3200 (n,s) instances, c=2, hw=64.
// Flatten rows R = g*2 + c (g = instance) -> Y (6400 x 64).
// norm over rows {2g,2g+1}; QKV = Y @ qkv_w^T + b (N=192);
// c=2 collapses linear attn to M[c][c'] = dot(q_c,k_c') (2x2), attn = v + M v;
// OUT = attn @ proj_w^T + proj_b + inp.  Output fp32.
//
// MFMA version: 200 blocks x 128 threads (2 waves). Block = 32 M-rows
// (16 instances); wave w owns M-tile w (16 rows). mfma_f32_16x16x32_f16,
// K=64 -> 2 k-steps; GEMM1 N-tiles 0..11 (q:0-3, k:4-7, v:8-11), GEMM2 4.
// Weights staged fp32->f16 in LDS once per block, XOR-swizzled (row&7)<<4.
// A-fragments built directly from registers after an in-fragment-layout norm.

typedef _Float16 half8 __attribute__((ext_vector_type(8)));
typedef _Float16 half4 __attribute__((ext_vector_type(4)));
typedef float    f32x4 __attribute__((ext_vector_type(4)));

// byte offset into an LDS tile with 64-f16 (128 B) row stride, 16B-chunk XOR swizzle
__device__ __forceinline__ int swz(int row, int colByte) {
    return row * 128 + (colByte ^ ((row & 7) << 4));
}

__global__ __launch_bounds__(128)
void attn_mfma(const float* __restrict__ inp,
               const float* __restrict__ qkv_w,
               const float* __restrict__ qkv_b,
               const float* __restrict__ proj_w,
               const float* __restrict__ proj_b,
               float* __restrict__ out)
{
    __shared__ _Float16 w_lds[192 * 64];   // qkv_w, f16, swizzled
    __shared__ _Float16 p_lds[64 * 64];    // proj_w, f16, swizzled
    __shared__ _Float16 a_lds[32 * 64];    // attn tile, f16, swizzled

    const int tid = threadIdx.x;
    const int w   = tid >> 6;      // wave id = M-tile
    const int l   = tid & 63;      // lane
    const int lr  = l & 15;        // fragment row/col index
    const int lg  = l >> 4;        // k-group (0..3)

    // ---------------- stage weights: global fp32 (coalesced) -> LDS f16 ----------------
    #pragma unroll
    for (int k = 0; k < 24; ++k) {                 // 12288 floats = 3072 float4
        const int idx4 = tid + k * 128;
        const float4 v = reinterpret_cast<const float4*>(qkv_w)[idx4];
        const int row  = idx4 >> 4;                // 16 float4 per 64-float row
        const int colB = (idx4 & 15) * 8;          // byte offset (4 f16 = 8 B)
        half4 h = { (_Float16)v.x, (_Float16)v.y, (_Float16)v.z, (_Float16)v.w };
        *reinterpret_cast<half4*>(reinterpret_cast<char*>(w_lds) + swz(row, colB)) = h;
    }
    #pragma unroll
    for (int k = 0; k < 8; ++k) {                  // 4096 floats = 1024 float4
        const int idx4 = tid + k * 128;
        const float4 v = reinterpret_cast<const float4*>(proj_w)[idx4];
        const int row  = idx4 >> 4;
        const int colB = (idx4 & 15) * 8;
        half4 h = { (_Float16)v.x, (_Float16)v.y, (_Float16)v.z, (_Float16)v.w };
        *reinterpret_cast<half4*>(reinterpret_cast<char*>(p_lds) + swz(row, colB)) = h;
    }

    // ---------------- load own Y-row span + InstanceNorm (in fragment layout) ----------------
    // lane owns Y-row R = blk*32 + 16w + lr, k-cols [lg*8, lg*8+8) and +32.
    const int lrow = (w << 4) | lr;
    const int R    = blockIdx.x * 32 + lrow;
    const int g    = R >> 1;                 // instance
    const int c    = R & 1;                  // channel
    const int n    = g >> 7;
    const int s    = g & 127;
    const int rowbase = ((n * 2 + c) * 128 + s) * 64;   // float index of row start
    const int col0 = lg * 8;

    const float4 x0a = *reinterpret_cast<const float4*>(inp + rowbase + col0);
    const float4 x0b = *reinterpret_cast<const float4*>(inp + rowbase + col0 + 4);
    const float4 x1a = *reinterpret_cast<const float4*>(inp + rowbase + col0 + 32);
    const float4 x1b = *reinterpret_cast<const float4*>(inp + rowbase + col0 + 36);

    float s1 = (x0a.x + x0a.y) + (x0a.z + x0a.w) + (x0b.x + x0b.y) + (x0b.z + x0b.w)
             + (x1a.x + x1a.y) + (x1a.z + x1a.w) + (x1b.x + x1b.y) + (x1b.z + x1b.w);
    float s2 = x0a.x*x0a.x + x0a.y*x0a.y + x0a.z*x0a.z + x0a.w*x0a.w
             + x0b.x*x0b.x + x0b.y*x0b.y + x0b.z*x0b.z + x0b.w*x0b.w
             + x1a.x*x1a.x + x1a.y*x1a.y + x1a.z*x1a.z + x1a.w*x1a.w
             + x1b.x*x1b.x + x1b.y*x1b.y + x1b.z*x1b.z + x1b.w*x1b.w;
    // reduce over row pair (xor 1) and the 4 k-groups (xor 16, 32) = the 128 values of instance g
    s1 += __shfl_xor(s1, 1);  s2 += __shfl_xor(s2, 1);
    s1 += __shfl_xor(s1, 16); s2 += __shfl_xor(s2, 16);
    s1 += __shfl_xor(s1, 32); s2 += __shfl_xor(s2, 32);
    const float mean = s1 * (1.0f / 128.0f);
    const float var  = s2 * (1.0f / 128.0f) - mean * mean;   // biased, like jnp.var
    const float rs   = rsqrtf(var + EPS);

    // A-fragments (k-step 0 and 1) directly in registers
    half8 a0, a1;
    a0[0]=(_Float16)((x0a.x-mean)*rs); a0[1]=(_Float16)((x0a.y-mean)*rs);
    a0[2]=(_Float16)((x0a.z-mean)*rs); a0[3]=(_Float16)((x0a.w-mean)*rs);
    a0[4]=(_Float16)((x0b.x-mean)*rs); a0[5]=(_Float16)((x0b.y-mean)*rs);
    a0[6]=(_Float16)((x0b.z-mean)*rs); a0[7]=(_Float16)((x0b.w-mean)*rs);
    a1[0]=(_Float16)((x1a.x-mean)*rs); a1[1]=(_Float16)((x1a.y-mean)*rs);
    a1[2]=(_Float16)((x1a.z-mean)*rs); a1[3]=(_Float16)((x1a.w-mean)*rs);
    a1[4]=(_Float16)((x1b.x-mean)*rs); a1[5]=(_Float16)((x1b.y-mean)*rs);
    a1[6]=(_Float16)((x1b.z-mean)*rs); a1[7]=(_Float16)((x1b.w-mean)*rs);

    __syncthreads();

    // ---------------- GEMM1: QKV accumulators, 12 N-tiles x 2 k-steps ----------------
    f32x4 acc[12];
    #pragma unroll
    for (int nt = 0; nt < 12; ++nt) acc[nt] = f32x4{0.f, 0.f, 0.f, 0.f};

    #pragma unroll
    for (int nt = 0; nt < 12; ++nt) {
        const int o = nt * 16 + lr;            // weight row = output column
        const half8 b0 = *reinterpret_cast<const half8*>(
            reinterpret_cast<const char*>(w_lds) + swz(o, lg * 16));
        const half8 b1 = *reinterpret_cast<const half8*>(
            reinterpret_cast<const char*>(w_lds) + swz(o, lg * 16 + 64));
        acc[nt] = __builtin_amdgcn_mfma_f32_16x16x32_f16(a0, b0, acc[nt], 0, 0, 0);
        acc[nt] = __builtin_amdgcn_mfma_f32_16x16x32_f16(a1, b1, acc[nt], 0, 0, 0);
    }
    // biases (per output column o = nt*16+lr, same for all 4 C-rows)
    #pragma unroll
    for (int nt = 0; nt < 12; ++nt) {
        const float b = qkv_b[nt * 16 + lr];
        acc[nt].x += b; acc[nt].y += b; acc[nt].z += b; acc[nt].w += b;
    }

    // ---------------- 2x2 M per instance + attn (in registers) ----------------
    // C-layout: lane holds cols o=nt*16+lr of rows m = 16w + lg*4 + r (r=0..3).
    // rows (4r0..) = instances iA (r 0,1) and iB (r 2,3); q: nt 0-3, k: 4-7, v: 8-11.
    float p[8] = {0.f,0.f,0.f,0.f,0.f,0.f,0.f,0.f}; // [instA 00,01,10,11 | instB ...]
    #pragma unroll
    for (int nt = 0; nt < 4; ++nt) {
        const f32x4 q = acc[nt], k = acc[4 + nt];
        p[0] = fmaf(q.x, k.x, p[0]);  p[1] = fmaf(q.x, k.y, p[1]);
        p[2] = fmaf(q.y, k.x, p[2]);  p[3] = fmaf(q.y, k.y, p[3]);
        p[4] = fmaf(q.z, k.z, p[4]);  p[5] = fmaf(q.z, k.w, p[5]);
        p[6] = fmaf(q.w, k.z, p[6]);  p[7] = fmaf(q.w, k.w, p[7]);
    }
    #pragma unroll
    for (int m = 8; m >= 1; m >>= 1) {     // reduce the 64 o-cols: 16 lanes x 4 nt
        #pragma unroll
        for (int z = 0; z < 8; ++z) p[z] += __shfl_xor(p[z], m);
    }
    // attn[0] = v0*(1+M00) + M01*v1 ; attn[1] = M10*v0 + v1*(1+M11)
    #pragma unroll
    for (int nt = 0; nt < 4; ++nt) {
        const f32x4 v = acc[8 + nt];
        float av[4];
        av[0] = v.x + fmaf(p[0], v.x, p[1] * v.y);
        av[1] = v.y + fmaf(p[2], v.x, p[3] * v.y);
        av[2] = v.z + fmaf(p[4], v.z, p[5] * v.w);
        av[3] = v.w + fmaf(p[6], v.z, p[7] * v.w);
        #pragma unroll
        for (int r = 0; r < 4; ++r) {
            const int rowl = (w << 4) + lg * 4 + r;
            const int colB = (nt * 16 + lr) * 2;
            *reinterpret_cast<_Float16*>(
                reinterpret_cast<char*>(a_lds) + swz(rowl, colB)) = (_Float16)av[r];
        }
    }
    __syncthreads();

    // ---------------- GEMM2: attn @ proj^T ----------------
    const half8 a20 = *reinterpret_cast<const half8*>(
        reinterpret_cast<const char*>(a_lds) + swz(lrow, lg * 16));
    const half8 a21 = *reinterpret_cast<const half8*>(
        reinterpret_cast<const char*>(a_lds) + swz(lrow, lg * 16 + 64));
    f32x4 acc2[4];
    #pragma unroll
    for (int nt = 0; nt < 4; ++nt) acc2[nt] = f32x4{0.f, 0.f, 0.f, 0.f};
    #pragma unroll
    for (int nt = 0; nt < 4; ++nt) {
        const int o = nt * 16 + lr;
        const half8 b0 = *reinterpret_cast<const half8*>(
            reinterpret_cast<const char*>(p_lds) + swz(o, lg * 16));
        const half8 b1 = *reinterpret_cast<const half8*>(
            reinterpret_cast<const char*>(p_lds) + swz(o, lg * 16 + 64));
        acc2[nt] = __builtin_amdgcn_mfma_f32_16x16x32_f16(a20, b0, acc2[nt], 0, 0, 0);
        acc2[nt] = __builtin_amdgcn_mfma_f32_16x16x32_f16(a21, b1, acc2[nt], 0, 0, 0);
    }

    // ---------------- epilogue: + proj_b + residual, fp32 store ----------------
    #pragma unroll
    for (int nt = 0; nt < 4; ++nt) {
        const int col = nt * 16 + lr;
        const float pb = proj_b[col];
        #pragma unroll
        for (int r = 0; r < 4; ++r) {
            const int Rl = (w << 4) + lg * 4 + r;
            const int Rg = blockIdx.x * 32 + Rl;
            const int gi = Rg >> 1, cc = Rg & 1;
            const int nn = gi >> 7, ss = gi & 127;
            const int addr = ((nn * 2 + cc) * 128 + ss) * 64 + col;
            const float a = (r == 0) ? acc2[nt].x : (r == 1) ? acc2[nt].y
                          : (r == 2) ? acc2[nt].z : acc2[nt].w;
            out[addr] = a + pb + inp[addr];
        }
    }
}

extern "C" void kernel_launch(void* const* d_in, const int* in_sizes, int n_in,
                              void* d_out, int out_size, void* d_ws, size_t ws_size,
                              hipStream_t stream) {
    const float* inp    = (const float*)d_in[0];
    const float* qkv_w  = (const float*)d_in[1];
    const float* qkv_b  = (const float*)d_in[2];
    const float* proj_w = (const float*)d_in[3];
    const float* proj_b = (const float*)d_in[4];
    float* out = (float*)d_out;

    // 3200 instances / 16 per block = 200 blocks x 128 threads
    attn_mfma<<<dim3(200), dim3(128), 0, stream>>>(inp, qkv_w, qkv_b, proj_w, proj_b, out);
}